// Round 4
// baseline (26.447 us; speedup 1.0000x reference)
//
#include <hip/hip_runtime.h>

// Problem shape is fixed by setup_inputs(): x is (8, 192, 64, 64) float32.
// Hardcode ALL sizing so the captured graph cannot depend on host-side
// in_sizes contents at capture time.
constexpr int kCH = 192;
constexpr int kHWp = 4096;                       // 64*64 elements per (b,c) plane
constexpr long long kTot = 8LL * 192 * 4096;     // 6,291,456 elements
constexpr int kBlocks = (int)(kTot / kHWp);      // 1536 blocks, one plane each

__device__ __forceinline__ float softplus_f(float x) {
    // stable: max(x,0) + log(1 + exp(-|x|)); arg of logf is in [1,2]
    return fmaxf(x, 0.0f) + logf(1.0f + __expf(-fabsf(x)));
}

__device__ __forceinline__ float tanh_fast(float x) {
    float e = __expf(-2.0f * fabsf(x));
    float t = (1.0f - e) / (1.0f + e);
    return (x < 0.0f) ? -t : t;
}

__device__ __forceinline__ float sigmoid_f(float x) {
    return 1.0f / (1.0f + __expf(-x));
}

__device__ __forceinline__ float eval_chain(
    float v,
    const float* sm0, const float* vb0, const float* tf0, bool g0,
    const float* sm1, const float* vb1, const float* tf1, bool g1,
    const float* sm2, const float* vb2, const float* tf2, bool g2,
    const float* sm3, float vb3)
{
    float h0[3], h1[3], h2[3];
#pragma unroll
    for (int i = 0; i < 3; ++i) h0[i] = fmaf(sm0[i], v, vb0[i]);
    if (g0) {
#pragma unroll
        for (int i = 0; i < 3; ++i) h0[i] = fmaf(tf0[i], tanh_fast(h0[i]), h0[i]);
    }
#pragma unroll
    for (int i = 0; i < 3; ++i) {
        float a = vb1[i];
        a = fmaf(sm1[i*3+0], h0[0], a);
        a = fmaf(sm1[i*3+1], h0[1], a);
        a = fmaf(sm1[i*3+2], h0[2], a);
        h1[i] = a;
    }
    if (g1) {
#pragma unroll
        for (int i = 0; i < 3; ++i) h1[i] = fmaf(tf1[i], tanh_fast(h1[i]), h1[i]);
    }
#pragma unroll
    for (int i = 0; i < 3; ++i) {
        float a = vb2[i];
        a = fmaf(sm2[i*3+0], h1[0], a);
        a = fmaf(sm2[i*3+1], h1[1], a);
        a = fmaf(sm2[i*3+2], h1[2], a);
        h2[i] = a;
    }
    if (g2) {
#pragma unroll
        for (int i = 0; i < 3; ++i) h2[i] = fmaf(tf2[i], tanh_fast(h2[i]), h2[i]);
    }
    float o = vb3;
    o = fmaf(sm3[0], h2[0], o);
    o = fmaf(sm3[1], h2[1], o);
    o = fmaf(sm3[2], h2[2], o);
    return o;
}

// One block per (b,c) plane: 256 threads x 16 elems (4 float4 at stride 1024).
// Each vector load/store instruction is a contiguous 1 KiB wave access.
__global__ void __launch_bounds__(256)
eb_kernel(const float* __restrict__ x,
          const float* __restrict__ m0, const float* __restrict__ m1,
          const float* __restrict__ m2, const float* __restrict__ m3,
          const float* __restrict__ b0, const float* __restrict__ b1,
          const float* __restrict__ b2, const float* __restrict__ b3,
          const float* __restrict__ f0, const float* __restrict__ f1,
          const float* __restrict__ f2,
          float* __restrict__ out)
{
    __shared__ float P[43];
    const int plane = blockIdx.x;
    const int c = plane % kCH;
    const int tid = threadIdx.x;

    if (tid < 43) {
        float v;
        if      (tid < 3)  v = softplus_f(m0[c*3 + tid]);
        else if (tid < 12) v = softplus_f(m1[c*9 + (tid-3)]);
        else if (tid < 21) v = softplus_f(m2[c*9 + (tid-12)]);
        else if (tid < 24) v = softplus_f(m3[c*3 + (tid-21)]);
        else if (tid < 27) v = b0[c*3 + (tid-24)];
        else if (tid < 30) v = b1[c*3 + (tid-27)];
        else if (tid < 33) v = b2[c*3 + (tid-30)];
        else if (tid < 34) v = b3[c];
        else if (tid < 37) v = tanh_fast(f0[c*3 + (tid-34)]);
        else if (tid < 40) v = tanh_fast(f1[c*3 + (tid-37)]);
        else               v = tanh_fast(f2[c*3 + (tid-40)]);
        P[tid] = v;
    }
    __syncthreads();

    float sm0[3], sm1[9], sm2[9], sm3[3], vb0[3], vb1[3], vb2[3], vb3;
    float tf0[3], tf1[3], tf2[3];
#pragma unroll
    for (int i = 0; i < 3; ++i) sm0[i] = P[0 + i];
#pragma unroll
    for (int i = 0; i < 9; ++i) sm1[i] = P[3 + i];
#pragma unroll
    for (int i = 0; i < 9; ++i) sm2[i] = P[12 + i];
#pragma unroll
    for (int i = 0; i < 3; ++i) sm3[i] = P[21 + i];
#pragma unroll
    for (int i = 0; i < 3; ++i) vb0[i] = P[24 + i];
#pragma unroll
    for (int i = 0; i < 3; ++i) vb1[i] = P[27 + i];
#pragma unroll
    for (int i = 0; i < 3; ++i) vb2[i] = P[30 + i];
    vb3 = P[33];
#pragma unroll
    for (int i = 0; i < 3; ++i) tf0[i] = P[34 + i];
#pragma unroll
    for (int i = 0; i < 3; ++i) tf1[i] = P[37 + i];
#pragma unroll
    for (int i = 0; i < 3; ++i) tf2[i] = P[40 + i];

    // block-uniform gate flags (F params are zero in practice -> skip tanh work)
    const bool g0 = (tf0[0] != 0.0f) || (tf0[1] != 0.0f) || (tf0[2] != 0.0f);
    const bool g1 = (tf1[0] != 0.0f) || (tf1[1] != 0.0f) || (tf1[2] != 0.0f);
    const bool g2 = (tf2[0] != 0.0f) || (tf2[1] != 0.0f) || (tf2[2] != 0.0f);

    const long long pbase = (long long)plane * kHWp + (long long)tid * 4;

    // issue all 4 independent loads up front (stride 1024 elements)
    float4 xv[4];
#pragma unroll
    for (int j = 0; j < 4; ++j)
        xv[j] = *reinterpret_cast<const float4*>(x + pbase + j * 1024);

#pragma unroll
    for (int j = 0; j < 4; ++j) {
        float xin[4] = {xv[j].x, xv[j].y, xv[j].z, xv[j].w};
        float zq[4], lik[4];
#pragma unroll
        for (int k = 0; k < 4; ++k) {
            const float z = rintf(xin[k]);   // round half-to-even, matches jnp.round
            const float l = eval_chain(z - 0.5f, sm0, vb0, tf0, g0,
                                       sm1, vb1, tf1, g1, sm2, vb2, tf2, g2, sm3, vb3);
            const float u = eval_chain(z + 0.5f, sm0, vb0, tf0, g0,
                                       sm1, vb1, tf1, g1, sm2, vb2, tf2, g2, sm3, vb3);
            const float su = l + u;
            const float s = (su > 0.0f) ? -1.0f : ((su < 0.0f) ? 1.0f : 0.0f);
            float lk = fabsf(sigmoid_f(s * u) - sigmoid_f(s * l));
            lik[k] = fmaxf(lk, 1e-6f);
            zq[k] = z;
        }
        float4 zo;
        zo.x = zq[0]; zo.y = zq[1]; zo.z = zq[2]; zo.w = zq[3];
        float4 lo;
        lo.x = lik[0]; lo.y = lik[1]; lo.z = lik[2]; lo.w = lik[3];
        *reinterpret_cast<float4*>(out + pbase + j * 1024) = zo;
        *reinterpret_cast<float4*>(out + kTot + pbase + j * 1024) = lo;
    }
}

extern "C" void kernel_launch(void* const* d_in, const int* in_sizes, int n_in,
                              void* d_out, int out_size, void* d_ws, size_t ws_size,
                              hipStream_t stream) {
    const float* x  = (const float*)d_in[0];
    const float* m0 = (const float*)d_in[1];
    const float* m1 = (const float*)d_in[2];
    const float* m2 = (const float*)d_in[3];
    const float* m3 = (const float*)d_in[4];
    const float* b0 = (const float*)d_in[5];
    const float* b1 = (const float*)d_in[6];
    const float* b2 = (const float*)d_in[7];
    const float* b3 = (const float*)d_in[8];
    const float* f0 = (const float*)d_in[9];
    const float* f1 = (const float*)d_in[10];
    const float* f2 = (const float*)d_in[11];
    float* out = (float*)d_out;

    // Fixed problem size (8,192,64,64): grid is a compile-time constant so the
    // captured graph cannot depend on host-side size arrays.
    hipLaunchKernelGGL(eb_kernel, dim3(kBlocks), dim3(256), 0, stream,
                       x, m0, m1, m2, m3, b0, b1, b2, b3, f0, f1, f2, out);
}

// Round 5
// 21.677 us; speedup vs baseline: 1.2201x; 1.2201x over previous
//
#include <hip/hip_runtime.h>

// Fixed problem shape from setup_inputs(): x is (8, 192, 64, 64) float32.
constexpr int kCH = 192;
constexpr int kHWp = 4096;                        // 64*64 per (b,c) plane
constexpr long long kTot = 8LL * 192 * 4096;      // 6,291,456 elements
constexpr int kBlksPerPlane = 2;
constexpr int kBlocks = 1536 * kBlksPerPlane;     // 3072 blocks
constexpr int kElemsPerBlk = kHWp / kBlksPerPlane; // 2048 = 256 thr * 2 float4

__device__ __forceinline__ float softplus_f(float x) {
    return fmaxf(x, 0.0f) + logf(1.0f + __expf(-fabsf(x)));
}

__device__ __forceinline__ float tanh_fast(float x) {
    float e = __expf(-2.0f * fabsf(x));
    float t = (1.0f - e) / (1.0f + e);
    return (x < 0.0f) ? -t : t;
}

__device__ __forceinline__ float rcp_fast(float x) {
    return __builtin_amdgcn_rcpf(x);              // v_rcp_f32, ~1ulp
}

__device__ __forceinline__ float sigmoid_fast(float x) {
    return rcp_fast(1.0f + __expf(-x));
}

__device__ __forceinline__ float sigmoid_f(float x) {
    return 1.0f / (1.0f + __expf(-x));
}

// General gated chain (fallback when any tanh(F) gate is non-zero).
__device__ __forceinline__ float eval_chain(
    float v,
    const float* sm0, const float* vb0, const float* tf0, bool g0,
    const float* sm1, const float* vb1, const float* tf1, bool g1,
    const float* sm2, const float* vb2, const float* tf2, bool g2,
    const float* sm3, float vb3)
{
    float h0[3], h1[3], h2[3];
#pragma unroll
    for (int i = 0; i < 3; ++i) h0[i] = fmaf(sm0[i], v, vb0[i]);
    if (g0) {
#pragma unroll
        for (int i = 0; i < 3; ++i) h0[i] = fmaf(tf0[i], tanh_fast(h0[i]), h0[i]);
    }
#pragma unroll
    for (int i = 0; i < 3; ++i) {
        float a = vb1[i];
        a = fmaf(sm1[i*3+0], h0[0], a);
        a = fmaf(sm1[i*3+1], h0[1], a);
        a = fmaf(sm1[i*3+2], h0[2], a);
        h1[i] = a;
    }
    if (g1) {
#pragma unroll
        for (int i = 0; i < 3; ++i) h1[i] = fmaf(tf1[i], tanh_fast(h1[i]), h1[i]);
    }
#pragma unroll
    for (int i = 0; i < 3; ++i) {
        float a = vb2[i];
        a = fmaf(sm2[i*3+0], h1[0], a);
        a = fmaf(sm2[i*3+1], h1[1], a);
        a = fmaf(sm2[i*3+2], h1[2], a);
        h2[i] = a;
    }
    if (g2) {
#pragma unroll
        for (int i = 0; i < 3; ++i) h2[i] = fmaf(tf2[i], tanh_fast(h2[i]), h2[i]);
    }
    float o = vb3;
    o = fmaf(sm3[0], h2[0], o);
    o = fmaf(sm3[1], h2[1], o);
    o = fmaf(sm3[2], h2[2], o);
    return o;
}

__global__ void __launch_bounds__(256)
eb_kernel(const float* __restrict__ x,
          const float* __restrict__ m0, const float* __restrict__ m1,
          const float* __restrict__ m2, const float* __restrict__ m3,
          const float* __restrict__ b0, const float* __restrict__ b1,
          const float* __restrict__ b2, const float* __restrict__ b3,
          const float* __restrict__ f0, const float* __restrict__ f1,
          const float* __restrict__ f2,
          float* __restrict__ out)
{
    __shared__ float P[43];
    const int blk = blockIdx.x;
    const int plane = blk >> 1;                   // kBlksPerPlane == 2
    const int half = blk & 1;
    const int c = plane % kCH;
    const int tid = threadIdx.x;

    if (tid < 43) {
        float v;
        if      (tid < 3)  v = softplus_f(m0[c*3 + tid]);
        else if (tid < 12) v = softplus_f(m1[c*9 + (tid-3)]);
        else if (tid < 21) v = softplus_f(m2[c*9 + (tid-12)]);
        else if (tid < 24) v = softplus_f(m3[c*3 + (tid-21)]);
        else if (tid < 27) v = b0[c*3 + (tid-24)];
        else if (tid < 30) v = b1[c*3 + (tid-27)];
        else if (tid < 33) v = b2[c*3 + (tid-30)];
        else if (tid < 34) v = b3[c];
        else if (tid < 37) v = tanh_fast(f0[c*3 + (tid-34)]);
        else if (tid < 40) v = tanh_fast(f1[c*3 + (tid-37)]);
        else               v = tanh_fast(f2[c*3 + (tid-40)]);
        P[tid] = v;
    }
    __syncthreads();

    // block-uniform gate detection (F params are zero in practice)
    const bool g0 = (P[34] != 0.0f) || (P[35] != 0.0f) || (P[36] != 0.0f);
    const bool g1 = (P[37] != 0.0f) || (P[38] != 0.0f) || (P[39] != 0.0f);
    const bool g2 = (P[40] != 0.0f) || (P[41] != 0.0f) || (P[42] != 0.0f);

    const long long base = (long long)plane * kHWp
                         + (long long)half * kElemsPerBlk
                         + (long long)tid * 4;

    if (!(g0 || g1 || g2)) {
        // ---- FAST PATH: gates off -> whole chain is affine: o = w*z + b ----
        // collapse (each thread redundantly, ~45 ops, once per 8 elements)
        float t1[3], t2[3], u1[3], u2[3];
#pragma unroll
        for (int i = 0; i < 3; ++i) {
            t1[i] = P[3 + i*3 + 0] * P[0]
                  + P[3 + i*3 + 1] * P[1]
                  + P[3 + i*3 + 2] * P[2];
            u1[i] = P[3 + i*3 + 0] * P[24]
                  + P[3 + i*3 + 1] * P[25]
                  + P[3 + i*3 + 2] * P[26] + P[27 + i];
        }
#pragma unroll
        for (int i = 0; i < 3; ++i) {
            t2[i] = P[12 + i*3 + 0] * t1[0]
                  + P[12 + i*3 + 1] * t1[1]
                  + P[12 + i*3 + 2] * t1[2];
            u2[i] = P[12 + i*3 + 0] * u1[0]
                  + P[12 + i*3 + 1] * u1[1]
                  + P[12 + i*3 + 2] * u1[2] + P[30 + i];
        }
        const float w = P[21]*t2[0] + P[22]*t2[1] + P[23]*t2[2];
        const float bb = P[21]*u2[0] + P[22]*u2[1] + P[23]*u2[2] + P[33];
        const float bl = fmaf(-0.5f, w, bb);
        const float bu = fmaf( 0.5f, w, bb);

        float4 xv[2];
#pragma unroll
        for (int j = 0; j < 2; ++j)
            xv[j] = *reinterpret_cast<const float4*>(x + base + j * 1024);

#pragma unroll
        for (int j = 0; j < 2; ++j) {
            float xin[4] = {xv[j].x, xv[j].y, xv[j].z, xv[j].w};
            float zq[4], lik[4];
#pragma unroll
            for (int k = 0; k < 4; ++k) {
                const float z = rintf(xin[k]);          // matches jnp.round
                const float l = fmaf(w, z, bl);
                const float u = fmaf(w, z, bu);
                const float su = l + u;
                const float s = (su > 0.0f) ? -1.0f : ((su < 0.0f) ? 1.0f : 0.0f);
                float lk = fabsf(sigmoid_fast(s * u) - sigmoid_fast(s * l));
                lik[k] = fmaxf(lk, 1e-6f);
                zq[k] = z;
            }
            float4 zo; zo.x = zq[0]; zo.y = zq[1]; zo.z = zq[2]; zo.w = zq[3];
            float4 lo; lo.x = lik[0]; lo.y = lik[1]; lo.z = lik[2]; lo.w = lik[3];
            *reinterpret_cast<float4*>(out + base + j * 1024) = zo;
            *reinterpret_cast<float4*>(out + kTot + base + j * 1024) = lo;
        }
        return;
    }

    // ---- FALLBACK: general gated chain (block-uniform branch) ----
    float sm0[3], sm1[9], sm2[9], sm3[3], vb0[3], vb1[3], vb2[3], vb3;
    float tf0[3], tf1[3], tf2[3];
#pragma unroll
    for (int i = 0; i < 3; ++i) sm0[i] = P[0 + i];
#pragma unroll
    for (int i = 0; i < 9; ++i) sm1[i] = P[3 + i];
#pragma unroll
    for (int i = 0; i < 9; ++i) sm2[i] = P[12 + i];
#pragma unroll
    for (int i = 0; i < 3; ++i) sm3[i] = P[21 + i];
#pragma unroll
    for (int i = 0; i < 3; ++i) vb0[i] = P[24 + i];
#pragma unroll
    for (int i = 0; i < 3; ++i) vb1[i] = P[27 + i];
#pragma unroll
    for (int i = 0; i < 3; ++i) vb2[i] = P[30 + i];
    vb3 = P[33];
#pragma unroll
    for (int i = 0; i < 3; ++i) tf0[i] = P[34 + i];
#pragma unroll
    for (int i = 0; i < 3; ++i) tf1[i] = P[37 + i];
#pragma unroll
    for (int i = 0; i < 3; ++i) tf2[i] = P[40 + i];

#pragma unroll
    for (int j = 0; j < 2; ++j) {
        const float4 xv = *reinterpret_cast<const float4*>(x + base + j * 1024);
        float xin[4] = {xv.x, xv.y, xv.z, xv.w};
        float zq[4], lik[4];
#pragma unroll
        for (int k = 0; k < 4; ++k) {
            const float z = rintf(xin[k]);
            const float l = eval_chain(z - 0.5f, sm0, vb0, tf0, g0,
                                       sm1, vb1, tf1, g1, sm2, vb2, tf2, g2, sm3, vb3);
            const float u = eval_chain(z + 0.5f, sm0, vb0, tf0, g0,
                                       sm1, vb1, tf1, g1, sm2, vb2, tf2, g2, sm3, vb3);
            const float su = l + u;
            const float s = (su > 0.0f) ? -1.0f : ((su < 0.0f) ? 1.0f : 0.0f);
            float lk = fabsf(sigmoid_f(s * u) - sigmoid_f(s * l));
            lik[k] = fmaxf(lk, 1e-6f);
            zq[k] = z;
        }
        float4 zo; zo.x = zq[0]; zo.y = zq[1]; zo.z = zq[2]; zo.w = zq[3];
        float4 lo; lo.x = lik[0]; lo.y = lik[1]; lo.z = lik[2]; lo.w = lik[3];
        *reinterpret_cast<float4*>(out + base + j * 1024) = zo;
        *reinterpret_cast<float4*>(out + kTot + base + j * 1024) = lo;
    }
}

extern "C" void kernel_launch(void* const* d_in, const int* in_sizes, int n_in,
                              void* d_out, int out_size, void* d_ws, size_t ws_size,
                              hipStream_t stream) {
    const float* x  = (const float*)d_in[0];
    const float* m0 = (const float*)d_in[1];
    const float* m1 = (const float*)d_in[2];
    const float* m2 = (const float*)d_in[3];
    const float* m3 = (const float*)d_in[4];
    const float* b0 = (const float*)d_in[5];
    const float* b1 = (const float*)d_in[6];
    const float* b2 = (const float*)d_in[7];
    const float* b3 = (const float*)d_in[8];
    const float* f0 = (const float*)d_in[9];
    const float* f1 = (const float*)d_in[10];
    const float* f2 = (const float*)d_in[11];
    float* out = (float*)d_out;

    hipLaunchKernelGGL(eb_kernel, dim3(kBlocks), dim3(256), 0, stream,
                       x, m0, m1, m2, m3, b0, b1, b2, b3, f0, f1, f2, out);
}

// Round 7
// 20.448 us; speedup vs baseline: 1.2934x; 1.0601x over previous
//
#include <hip/hip_runtime.h>

// Fixed problem shape from setup_inputs(): x is (8, 192, 64, 64) float32.
constexpr int kCH = 192;
constexpr int kHWp = 4096;                        // 64*64 per (b,c) plane
constexpr long long kTot = 8LL * 192 * 4096;      // 6,291,456 elements
constexpr int kBlocks = 1536;                     // one block per (b,c) plane

typedef float f32x4 __attribute__((ext_vector_type(4)));   // native vector for NT builtins

__device__ __forceinline__ float softplus_f(float x) {
    return fmaxf(x, 0.0f) + logf(1.0f + __expf(-fabsf(x)));
}

__device__ __forceinline__ float tanh_fast(float x) {
    float e = __expf(-2.0f * fabsf(x));
    float t = (1.0f - e) / (1.0f + e);
    return (x < 0.0f) ? -t : t;
}

__device__ __forceinline__ float rcp_fast(float x) {
    return __builtin_amdgcn_rcpf(x);              // v_rcp_f32
}

__device__ __forceinline__ float sigmoid_fast(float x) {
    return rcp_fast(1.0f + __expf(-x));
}

__device__ __forceinline__ float sigmoid_f(float x) {
    return 1.0f / (1.0f + __expf(-x));
}

// General gated chain (fallback when any tanh(F) gate is non-zero).
__device__ __forceinline__ float eval_chain(
    float v,
    const float* sm0, const float* vb0, const float* tf0, bool g0,
    const float* sm1, const float* vb1, const float* tf1, bool g1,
    const float* sm2, const float* vb2, const float* tf2, bool g2,
    const float* sm3, float vb3)
{
    float h0[3], h1[3], h2[3];
#pragma unroll
    for (int i = 0; i < 3; ++i) h0[i] = fmaf(sm0[i], v, vb0[i]);
    if (g0) {
#pragma unroll
        for (int i = 0; i < 3; ++i) h0[i] = fmaf(tf0[i], tanh_fast(h0[i]), h0[i]);
    }
#pragma unroll
    for (int i = 0; i < 3; ++i) {
        float a = vb1[i];
        a = fmaf(sm1[i*3+0], h0[0], a);
        a = fmaf(sm1[i*3+1], h0[1], a);
        a = fmaf(sm1[i*3+2], h0[2], a);
        h1[i] = a;
    }
    if (g1) {
#pragma unroll
        for (int i = 0; i < 3; ++i) h1[i] = fmaf(tf1[i], tanh_fast(h1[i]), h1[i]);
    }
#pragma unroll
    for (int i = 0; i < 3; ++i) {
        float a = vb2[i];
        a = fmaf(sm2[i*3+0], h1[0], a);
        a = fmaf(sm2[i*3+1], h1[1], a);
        a = fmaf(sm2[i*3+2], h1[2], a);
        h2[i] = a;
    }
    if (g2) {
#pragma unroll
        for (int i = 0; i < 3; ++i) h2[i] = fmaf(tf2[i], tanh_fast(h2[i]), h2[i]);
    }
    float o = vb3;
    o = fmaf(sm3[0], h2[0], o);
    o = fmaf(sm3[1], h2[1], o);
    o = fmaf(sm3[2], h2[2], o);
    return o;
}

// One block per (b,c) plane: 256 threads x 16 elems (4 f32x4 at stride 1024).
// No LDS, no barrier: params are block-uniform -> scalar loads + uniform ALU.
__global__ void __launch_bounds__(256)
eb_kernel(const float* __restrict__ x,
          const float* __restrict__ m0, const float* __restrict__ m1,
          const float* __restrict__ m2, const float* __restrict__ m3,
          const float* __restrict__ b0, const float* __restrict__ b1,
          const float* __restrict__ b2, const float* __restrict__ b3,
          const float* __restrict__ f0, const float* __restrict__ f1,
          const float* __restrict__ f2,
          float* __restrict__ out)
{
    const int plane = blockIdx.x;
    const int c = plane % kCH;
    const int tid = threadIdx.x;
    const long long base = (long long)plane * kHWp + (long long)tid * 4;

    // gate check on raw F (tanh(0)==0 <=> f==0); block-uniform
    const bool gated =
        (f0[c*3+0] != 0.0f) || (f0[c*3+1] != 0.0f) || (f0[c*3+2] != 0.0f) ||
        (f1[c*3+0] != 0.0f) || (f1[c*3+1] != 0.0f) || (f1[c*3+2] != 0.0f) ||
        (f2[c*3+0] != 0.0f) || (f2[c*3+1] != 0.0f) || (f2[c*3+2] != 0.0f);

    if (!gated) {
        // ---- FAST PATH: chain is exactly affine: o = w*z + b ----
        // issue the 4 independent 1-KiB wave loads first
        f32x4 xv[4];
#pragma unroll
        for (int j = 0; j < 4; ++j)
            xv[j] = __builtin_nontemporal_load(
                        reinterpret_cast<const f32x4*>(x + base + j * 1024));

        // uniform collapse: w = sm3^T SM2 SM1 sm0 ; b = chained biases
        float a0[3], a3[3], t1[3], u1[3], t2[3], u2[3];
#pragma unroll
        for (int i = 0; i < 3; ++i) a0[i] = softplus_f(m0[c*3 + i]);
#pragma unroll
        for (int i = 0; i < 3; ++i) a3[i] = softplus_f(m3[c*3 + i]);
#pragma unroll
        for (int i = 0; i < 3; ++i) {
            const float s0 = softplus_f(m1[c*9 + i*3 + 0]);
            const float s1 = softplus_f(m1[c*9 + i*3 + 1]);
            const float s2 = softplus_f(m1[c*9 + i*3 + 2]);
            t1[i] = s0 * a0[0] + s1 * a0[1] + s2 * a0[2];
            u1[i] = s0 * b0[c*3+0] + s1 * b0[c*3+1] + s2 * b0[c*3+2] + b1[c*3 + i];
        }
#pragma unroll
        for (int i = 0; i < 3; ++i) {
            const float s0 = softplus_f(m2[c*9 + i*3 + 0]);
            const float s1 = softplus_f(m2[c*9 + i*3 + 1]);
            const float s2 = softplus_f(m2[c*9 + i*3 + 2]);
            t2[i] = s0 * t1[0] + s1 * t1[1] + s2 * t1[2];
            u2[i] = s0 * u1[0] + s1 * u1[1] + s2 * u1[2] + b2[c*3 + i];
        }
        const float w  = a3[0]*t2[0] + a3[1]*t2[1] + a3[2]*t2[2];
        const float bb = a3[0]*u2[0] + a3[1]*u2[1] + a3[2]*u2[2] + b3[c];
        const float bl = fmaf(-0.5f, w, bb);
        const float bu = fmaf( 0.5f, w, bb);

#pragma unroll
        for (int j = 0; j < 4; ++j) {
            f32x4 zo, lo;
#pragma unroll
            for (int k = 0; k < 4; ++k) {
                const float z = rintf(xv[j][k]);        // matches jnp.round
                const float l = fmaf(w, z, bl);
                const float u = fmaf(w, z, bu);
                // for s=+-1, |sig(s*u)-sig(s*l)| == |sig(u)-sig(l)|; s==0 guarded
                float d = fabsf(sigmoid_fast(u) - sigmoid_fast(l));
                d = ((l + u) == 0.0f) ? 0.0f : d;
                lo[k] = fmaxf(d, 1e-6f);
                zo[k] = z;
            }
            __builtin_nontemporal_store(zo,
                reinterpret_cast<f32x4*>(out + base + j * 1024));
            __builtin_nontemporal_store(lo,
                reinterpret_cast<f32x4*>(out + kTot + base + j * 1024));
        }
        return;
    }

    // ---- FALLBACK: general gated chain (block-uniform branch, exact ref semantics) ----
    float sm0[3], sm1[9], sm2[9], sm3[3], vb0[3], vb1[3], vb2[3], vb3;
    float tf0[3], tf1[3], tf2[3];
#pragma unroll
    for (int i = 0; i < 3; ++i) sm0[i] = softplus_f(m0[c*3 + i]);
#pragma unroll
    for (int i = 0; i < 9; ++i) sm1[i] = softplus_f(m1[c*9 + i]);
#pragma unroll
    for (int i = 0; i < 9; ++i) sm2[i] = softplus_f(m2[c*9 + i]);
#pragma unroll
    for (int i = 0; i < 3; ++i) sm3[i] = softplus_f(m3[c*3 + i]);
#pragma unroll
    for (int i = 0; i < 3; ++i) vb0[i] = b0[c*3 + i];
#pragma unroll
    for (int i = 0; i < 3; ++i) vb1[i] = b1[c*3 + i];
#pragma unroll
    for (int i = 0; i < 3; ++i) vb2[i] = b2[c*3 + i];
    vb3 = b3[c];
#pragma unroll
    for (int i = 0; i < 3; ++i) tf0[i] = tanh_fast(f0[c*3 + i]);
#pragma unroll
    for (int i = 0; i < 3; ++i) tf1[i] = tanh_fast(f1[c*3 + i]);
#pragma unroll
    for (int i = 0; i < 3; ++i) tf2[i] = tanh_fast(f2[c*3 + i]);
    const bool g0 = (tf0[0] != 0.0f) || (tf0[1] != 0.0f) || (tf0[2] != 0.0f);
    const bool g1 = (tf1[0] != 0.0f) || (tf1[1] != 0.0f) || (tf1[2] != 0.0f);
    const bool g2 = (tf2[0] != 0.0f) || (tf2[1] != 0.0f) || (tf2[2] != 0.0f);

#pragma unroll
    for (int j = 0; j < 4; ++j) {
        const f32x4 xv = *reinterpret_cast<const f32x4*>(x + base + j * 1024);
        f32x4 zo, lo;
#pragma unroll
        for (int k = 0; k < 4; ++k) {
            const float z = rintf(xv[k]);
            const float l = eval_chain(z - 0.5f, sm0, vb0, tf0, g0,
                                       sm1, vb1, tf1, g1, sm2, vb2, tf2, g2, sm3, vb3);
            const float u = eval_chain(z + 0.5f, sm0, vb0, tf0, g0,
                                       sm1, vb1, tf1, g1, sm2, vb2, tf2, g2, sm3, vb3);
            const float su = l + u;
            const float s = (su > 0.0f) ? -1.0f : ((su < 0.0f) ? 1.0f : 0.0f);
            float lk = fabsf(sigmoid_f(s * u) - sigmoid_f(s * l));
            lo[k] = fmaxf(lk, 1e-6f);
            zo[k] = z;
        }
        *reinterpret_cast<f32x4*>(out + base + j * 1024) = zo;
        *reinterpret_cast<f32x4*>(out + kTot + base + j * 1024) = lo;
    }
}

extern "C" void kernel_launch(void* const* d_in, const int* in_sizes, int n_in,
                              void* d_out, int out_size, void* d_ws, size_t ws_size,
                              hipStream_t stream) {
    const float* x  = (const float*)d_in[0];
    const float* m0 = (const float*)d_in[1];
    const float* m1 = (const float*)d_in[2];
    const float* m2 = (const float*)d_in[3];
    const float* m3 = (const float*)d_in[4];
    const float* b0 = (const float*)d_in[5];
    const float* b1 = (const float*)d_in[6];
    const float* b2 = (const float*)d_in[7];
    const float* b3 = (const float*)d_in[8];
    const float* f0 = (const float*)d_in[9];
    const float* f1 = (const float*)d_in[10];
    const float* f2 = (const float*)d_in[11];
    float* out = (float*)d_out;

    hipLaunchKernelGGL(eb_kernel, dim3(kBlocks), dim3(256), 0, stream,
                       x, m0, m1, m2, m3, b0, b1, b2, b3, f0, f1, f2, out);
}